// Round 1
// baseline (8935.029 us; speedup 1.0000x reference)
//
#include <hip/hip_runtime.h>

// GCN regressor: 3x (GEMM -> gather/scatter-add with symmetric norm -> bias+ReLU)
// -> segment-mean pool -> MLP head.
// Workspace layout (f32): buf0[N*128], buf1[N*128], dinv[N], sums[G*128], cnt[G]
// ~105 MB total.

constexpr int HID = 128;

__global__ __launch_bounds__(256) void k_deg(const int* __restrict__ dst,
                                             float* __restrict__ deg, int nE) {
    int i = blockIdx.x * 256 + threadIdx.x;
    if (i < nE) atomicAdd(&deg[dst[i]], 1.0f);
}

__global__ __launch_bounds__(256) void k_dinv(float* deg, int n) {
    int i = blockIdx.x * 256 + threadIdx.x;
    if (i < n) deg[i] = rsqrtf(deg[i] + 1.0f);  // +1 self-loop
}

// C[n,128] = A[n,128] @ W[128,128]; W staged in 64KB LDS, 8 rows/block.
__global__ __launch_bounds__(256) void k_gemm(const float* __restrict__ A,
                                              const float* __restrict__ W,
                                              float* __restrict__ C, int n) {
    __shared__ float Wl[HID * HID];
    for (int i = threadIdx.x; i < HID * HID; i += 256) Wl[i] = W[i];
    __syncthreads();
    int col = threadIdx.x & (HID - 1);
    int r0  = blockIdx.x * 8 + (threadIdx.x >> 7) * 4;
    if (r0 + 3 < n) {
        const float* a = A + (size_t)r0 * HID;
        float s0 = 0.f, s1 = 0.f, s2 = 0.f, s3 = 0.f;
#pragma unroll 8
        for (int k = 0; k < HID; ++k) {
            float w = Wl[k * HID + col];
            s0 += a[k] * w;
            s1 += a[HID + k] * w;
            s2 += a[2 * HID + k] * w;
            s3 += a[3 * HID + k] * w;
        }
        float* c = C + (size_t)r0 * HID + col;
        c[0] = s0; c[HID] = s1; c[2 * HID] = s2; c[3 * HID] = s3;
    } else {
        for (int r = r0; r < n && r < r0 + 4; ++r) {
            const float* a = A + (size_t)r * HID;
            float s = 0.f;
            for (int k = 0; k < HID; ++k) s += a[k] * Wl[k * HID + col];
            C[(size_t)r * HID + col] = s;
        }
    }
}

// One wave (64 lanes) per edge; each lane does 2 channels (float2 gather + 2 atomics).
__global__ __launch_bounds__(256) void k_scatter(const int* __restrict__ src,
                                                 const int* __restrict__ dst,
                                                 const float* __restrict__ dinv,
                                                 const float* __restrict__ hw,
                                                 float* __restrict__ agg, int nE) {
    long long t = (long long)blockIdx.x * 256 + threadIdx.x;
    int e = (int)(t >> 6);
    if (e >= nE) return;
    int c = ((int)t & 63) * 2;
    int s = src[e], d = dst[e];
    float w = dinv[s] * dinv[d];
    const float2 v = *(const float2*)(hw + (size_t)s * HID + c);
    float* p = agg + (size_t)d * HID + c;
    atomicAdd(p, v.x * w);
    atomicAdd(p + 1, v.y * w);
}

// out = relu(agg + hw*dinv^2 (self-loop) + b). out may alias hw (elementwise).
__global__ __launch_bounds__(256) void k_fuse(const float* __restrict__ agg,
                                              const float* hw,
                                              const float* __restrict__ dinv,
                                              const float* __restrict__ b,
                                              float* out, int n) {
    int t = blockIdx.x * 256 + threadIdx.x;
    if (t >= n * HID) return;
    int node = t >> 7, c = t & (HID - 1);
    float di = dinv[node];
    float v = agg[t] + hw[t] * di * di + b[c];
    out[t] = fmaxf(v, 0.0f);
}

__global__ __launch_bounds__(256) void k_count(const int* __restrict__ batch,
                                               float* __restrict__ cnt, int n) {
    int i = blockIdx.x * 256 + threadIdx.x;
    if (i < n) atomicAdd(&cnt[batch[i]], 1.0f);
}

__global__ __launch_bounds__(256) void k_poolsum(const int* __restrict__ batch,
                                                 const float* __restrict__ h,
                                                 float* __restrict__ sums, int n) {
    int t = blockIdx.x * 256 + threadIdx.x;
    if (t >= n * HID) return;
    int node = t >> 7, c = t & (HID - 1);
    atomicAdd(&sums[(size_t)batch[node] * HID + c], h[t]);
}

// One 64-lane wave per graph: hidden[j]=relu(pooled·lw1[:,j]+lb1[j]); out=hidden·lw2+lb2.
__global__ __launch_bounds__(64) void k_mlp(const float* __restrict__ sums,
                                            const float* __restrict__ cnt,
                                            const float* __restrict__ lw1,
                                            const float* __restrict__ lb1,
                                            const float* __restrict__ lw2,
                                            const float* __restrict__ lb2,
                                            float* __restrict__ out) {
    int g = blockIdx.x;
    int j = threadIdx.x;  // 0..63
    float inv = 1.0f / fmaxf(cnt[g], 1.0f);
    const float* srow = sums + (size_t)g * HID;
    float acc = lb1[j];
#pragma unroll 8
    for (int k = 0; k < HID; ++k) acc += srow[k] * inv * lw1[k * 64 + j];
    acc = fmaxf(acc, 0.0f);
    float prod = acc * lw2[j];
#pragma unroll
    for (int off = 32; off > 0; off >>= 1) prod += __shfl_down(prod, off);
    if (j == 0) out[g] = prod + lb2[0];
}

extern "C" void kernel_launch(void* const* d_in, const int* in_sizes, int n_in,
                              void* d_out, int out_size, void* d_ws, size_t ws_size,
                              hipStream_t stream) {
    const float* x   = (const float*)d_in[0];
    const int*   ei  = (const int*)d_in[1];
    const int*   bat = (const int*)d_in[2];
    const float* W1  = (const float*)d_in[3];
    const float* b1  = (const float*)d_in[4];
    const float* W2  = (const float*)d_in[5];
    const float* b2  = (const float*)d_in[6];
    const float* W3  = (const float*)d_in[7];
    const float* b3  = (const float*)d_in[8];
    const float* lw1 = (const float*)d_in[9];
    const float* lb1 = (const float*)d_in[10];
    const float* lw2 = (const float*)d_in[11];
    const float* lb2 = (const float*)d_in[12];
    float* out = (float*)d_out;

    const int nN = in_sizes[2];       // 100000
    const int nE = in_sizes[1] / 2;   // 3200000
    const int G  = out_size;          // 4096
    const int* src = ei;
    const int* dst = ei + nE;

    float* buf0 = (float*)d_ws;
    float* buf1 = buf0 + (size_t)nN * HID;
    float* dinv = buf1 + (size_t)nN * HID;
    float* sums = dinv + nN;
    float* cnt  = sums + (size_t)G * HID;

    // degrees -> dinv
    hipMemsetAsync(dinv, 0, sizeof(float) * nN, stream);
    k_deg<<<(nE + 255) / 256, 256, 0, stream>>>(dst, dinv, nE);
    k_dinv<<<(nN + 255) / 256, 256, 0, stream>>>(dinv, nN);

    const int gemmGrid = (nN + 7) / 8;
    const int elemGrid = (nN * HID + 255) / 256;
    const int scatGrid = (int)(((long long)nE * 64 + 255) / 256);
    const size_t hbytes = sizeof(float) * (size_t)nN * HID;

    // layer 1: x -> buf0 (h@W); agg into buf1; fused relu -> buf0
    k_gemm<<<gemmGrid, 256, 0, stream>>>(x, W1, buf0, nN);
    hipMemsetAsync(buf1, 0, hbytes, stream);
    k_scatter<<<scatGrid, 256, 0, stream>>>(src, dst, dinv, buf0, buf1, nE);
    k_fuse<<<elemGrid, 256, 0, stream>>>(buf1, buf0, dinv, b1, buf0, nN);

    // layer 2
    k_gemm<<<gemmGrid, 256, 0, stream>>>(buf0, W2, buf1, nN);
    hipMemsetAsync(buf0, 0, hbytes, stream);
    k_scatter<<<scatGrid, 256, 0, stream>>>(src, dst, dinv, buf1, buf0, nE);
    k_fuse<<<elemGrid, 256, 0, stream>>>(buf0, buf1, dinv, b2, buf1, nN);

    // layer 3
    k_gemm<<<gemmGrid, 256, 0, stream>>>(buf1, W3, buf0, nN);
    hipMemsetAsync(buf1, 0, hbytes, stream);
    k_scatter<<<scatGrid, 256, 0, stream>>>(src, dst, dinv, buf0, buf1, nE);
    k_fuse<<<elemGrid, 256, 0, stream>>>(buf1, buf0, dinv, b3, buf0, nN);

    // pool (sums+cnt contiguous -> single memset)
    hipMemsetAsync(sums, 0, sizeof(float) * ((size_t)G * HID + G), stream);
    k_count<<<(nN + 255) / 256, 256, 0, stream>>>(bat, cnt, nN);
    k_poolsum<<<elemGrid, 256, 0, stream>>>(bat, buf0, sums, nN);

    // head
    k_mlp<<<G, 64, 0, stream>>>(sums, cnt, lw1, lb1, lw2, lb2, out);
}

// Round 2
// 1994.048 us; speedup vs baseline: 4.4809x; 4.4809x over previous
//
#include <hip/hip_runtime.h>

// GCN regressor: CSR-by-dst gather-reduce version.
// Per call: build dst-CSR (hist -> scan -> bucket), then 3x (GEMM -> fused
// gather/agg+bias+ReLU), pool fused into layer-3 agg, MLP head.

constexpr int HID = 128;

// ---------------- CSR build ----------------
__global__ __launch_bounds__(256) void k_hist(const int* __restrict__ dst,
                                              int* __restrict__ cnt, int nE) {
    int i = blockIdx.x * 256 + threadIdx.x;
    if (i < nE) atomicAdd(&cnt[dst[i]], 1);
}

__global__ __launch_bounds__(256) void k_dinv(const int* __restrict__ cnt,
                                              float* __restrict__ dinv, int n) {
    int i = blockIdx.x * 256 + threadIdx.x;
    if (i < n) dinv[i] = rsqrtf((float)cnt[i] + 1.0f);  // +1 self-loop
}

// chunked exclusive scan: 1024 elems/block (256 thr x 4)
__global__ __launch_bounds__(256) void k_scan1(const int* __restrict__ cnt,
                                               int* __restrict__ offs,
                                               int* __restrict__ partials, int n) {
    __shared__ int lds[256];
    int tid = threadIdx.x;
    int base = blockIdx.x * 1024 + tid * 4;
    int a0 = (base + 0 < n) ? cnt[base + 0] : 0;
    int a1 = (base + 1 < n) ? cnt[base + 1] : 0;
    int a2 = (base + 2 < n) ? cnt[base + 2] : 0;
    int a3 = (base + 3 < n) ? cnt[base + 3] : 0;
    int s = a0 + a1 + a2 + a3;
    lds[tid] = s;
    __syncthreads();
    for (int off = 1; off < 256; off <<= 1) {
        int v = (tid >= off) ? lds[tid - off] : 0;
        __syncthreads();
        lds[tid] += v;
        __syncthreads();
    }
    int excl = lds[tid] - s;
    if (tid == 255) partials[blockIdx.x] = lds[255];
    if (base + 0 < n) offs[base + 0] = excl;
    if (base + 1 < n) offs[base + 1] = excl + a0;
    if (base + 2 < n) offs[base + 2] = excl + a0 + a1;
    if (base + 3 < n) offs[base + 3] = excl + a0 + a1 + a2;
}

__global__ void k_scan2(int* partials, int nP) {
    int run = 0;
    for (int i = 0; i < nP; ++i) { int t = partials[i]; partials[i] = run; run += t; }
}

__global__ __launch_bounds__(256) void k_scan3(int* __restrict__ offs,
                                               const int* __restrict__ partials,
                                               int* __restrict__ cursor, int n, int nE) {
    int i = blockIdx.x * 256 + threadIdx.x;
    if (i < n) {
        int v = offs[i] + partials[i >> 10];
        offs[i] = v;
        cursor[i] = v;
    }
    if (i == 0) offs[n] = nE;
}

__global__ __launch_bounds__(256) void k_bucket(const int* __restrict__ src,
                                                const int* __restrict__ dst,
                                                int* __restrict__ cursor,
                                                int* __restrict__ esrc, int nE) {
    int e = blockIdx.x * 256 + threadIdx.x;
    if (e >= nE) return;
    int pos = atomicAdd(&cursor[dst[e]], 1);
    esrc[pos] = src[e];
}

// ---------------- GEMM: C[n,128] = A[n,128] @ W[128,128] ----------------
__global__ __launch_bounds__(256) void k_gemm(const float* __restrict__ A,
                                              const float* __restrict__ W,
                                              float* __restrict__ C, int n) {
    __shared__ float Wl[HID * HID];
    for (int i = threadIdx.x; i < HID * HID; i += 256) Wl[i] = W[i];
    __syncthreads();
    int col = threadIdx.x & (HID - 1);
    int r0  = blockIdx.x * 8 + (threadIdx.x >> 7) * 4;
    if (r0 + 3 < n) {
        const float* a = A + (size_t)r0 * HID;
        float s0 = 0.f, s1 = 0.f, s2 = 0.f, s3 = 0.f;
#pragma unroll 8
        for (int k = 0; k < HID; ++k) {
            float w = Wl[k * HID + col];
            s0 += a[k] * w;
            s1 += a[HID + k] * w;
            s2 += a[2 * HID + k] * w;
            s3 += a[3 * HID + k] * w;
        }
        float* c = C + (size_t)r0 * HID + col;
        c[0] = s0; c[HID] = s1; c[2 * HID] = s2; c[3 * HID] = s3;
    } else {
        for (int r = r0; r < n && r < r0 + 4; ++r) {
            const float* a = A + (size_t)r * HID;
            float s = 0.f;
            for (int k = 0; k < HID; ++k) s += a[k] * Wl[k * HID + col];
            C[(size_t)r * HID + col] = s;
        }
    }
}

// ---------------- fused gather-aggregate + bias + ReLU (+ optional pool) ---
// one wave per dst node; lane owns 2 channels.
__global__ __launch_bounds__(256) void k_agg(const int* __restrict__ row_start,
                                             const int* __restrict__ esrc,
                                             const float* __restrict__ dinv,
                                             const float* __restrict__ hw,
                                             const float* __restrict__ bias,
                                             float* __restrict__ out, int n,
                                             float* __restrict__ pool_sums,
                                             const int* __restrict__ batch) {
    int t = blockIdx.x * 256 + threadIdx.x;
    int node = t >> 6;
    if (node >= n) return;
    int c = (t & 63) * 2;
    int e0 = row_start[node], e1 = row_start[node + 1];
    float dd = dinv[node];
    float ax = 0.f, ay = 0.f;
    int e = e0;
    for (; e + 2 <= e1; e += 2) {
        int sa = esrc[e], sb = esrc[e + 1];
        float wa = dinv[sa] * dd, wb = dinv[sb] * dd;
        float2 va = *(const float2*)(hw + (size_t)sa * HID + c);
        float2 vb = *(const float2*)(hw + (size_t)sb * HID + c);
        ax += va.x * wa + vb.x * wb;
        ay += va.y * wa + vb.y * wb;
    }
    if (e < e1) {
        int sa = esrc[e];
        float wa = dinv[sa] * dd;
        float2 va = *(const float2*)(hw + (size_t)sa * HID + c);
        ax += va.x * wa;
        ay += va.y * wa;
    }
    float2 hv = *(const float2*)(hw + (size_t)node * HID + c);
    ax += hv.x * dd * dd + bias[c];
    ay += hv.y * dd * dd + bias[c + 1];
    ax = fmaxf(ax, 0.f);
    ay = fmaxf(ay, 0.f);
    if (pool_sums) {
        float* p = &pool_sums[(size_t)batch[node] * HID + c];
        atomicAdd(p, ax);
        atomicAdd(p + 1, ay);
    } else {
        *(float2*)(out + (size_t)node * HID + c) = make_float2(ax, ay);
    }
}

// ---------------- pooling / head ----------------
__global__ __launch_bounds__(256) void k_count(const int* __restrict__ batch,
                                               float* __restrict__ cnt, int n) {
    int i = blockIdx.x * 256 + threadIdx.x;
    if (i < n) atomicAdd(&cnt[batch[i]], 1.0f);
}

__global__ __launch_bounds__(64) void k_mlp(const float* __restrict__ sums,
                                            const float* __restrict__ cnt,
                                            const float* __restrict__ lw1,
                                            const float* __restrict__ lb1,
                                            const float* __restrict__ lw2,
                                            const float* __restrict__ lb2,
                                            float* __restrict__ out) {
    int g = blockIdx.x;
    int j = threadIdx.x;
    float inv = 1.0f / fmaxf(cnt[g], 1.0f);
    const float* srow = sums + (size_t)g * HID;
    float acc = lb1[j];
#pragma unroll 8
    for (int k = 0; k < HID; ++k) acc += srow[k] * inv * lw1[k * 64 + j];
    acc = fmaxf(acc, 0.0f);
    float prod = acc * lw2[j];
#pragma unroll
    for (int off = 32; off > 0; off >>= 1) prod += __shfl_down(prod, off);
    if (j == 0) out[g] = prod + lb2[0];
}

// ---------------- legacy fallback (atomic scatter) ----------------
__global__ __launch_bounds__(256) void k_scatter(const int* __restrict__ src,
                                                 const int* __restrict__ dst,
                                                 const float* __restrict__ dinv,
                                                 const float* __restrict__ hw,
                                                 float* __restrict__ agg, int nE) {
    long long t = (long long)blockIdx.x * 256 + threadIdx.x;
    int e = (int)(t >> 6);
    if (e >= nE) return;
    int c = ((int)t & 63) * 2;
    int s = src[e], d = dst[e];
    float w = dinv[s] * dinv[d];
    const float2 v = *(const float2*)(hw + (size_t)s * HID + c);
    float* p = agg + (size_t)d * HID + c;
    atomicAdd(p, v.x * w);
    atomicAdd(p + 1, v.y * w);
}

__global__ __launch_bounds__(256) void k_fuse(const float* __restrict__ agg,
                                              const float* hw,
                                              const float* __restrict__ dinv,
                                              const float* __restrict__ b,
                                              float* out, int n) {
    int t = blockIdx.x * 256 + threadIdx.x;
    if (t >= n * HID) return;
    int node = t >> 7, c = t & (HID - 1);
    float di = dinv[node];
    float v = agg[t] + hw[t] * di * di + b[c];
    out[t] = fmaxf(v, 0.0f);
}

__global__ __launch_bounds__(256) void k_poolsum(const int* __restrict__ batch,
                                                 const float* __restrict__ h,
                                                 float* __restrict__ sums, int n) {
    int t = blockIdx.x * 256 + threadIdx.x;
    if (t >= n * HID) return;
    int node = t >> 7, c = t & (HID - 1);
    atomicAdd(&sums[(size_t)batch[node] * HID + c], h[t]);
}

extern "C" void kernel_launch(void* const* d_in, const int* in_sizes, int n_in,
                              void* d_out, int out_size, void* d_ws, size_t ws_size,
                              hipStream_t stream) {
    const float* x   = (const float*)d_in[0];
    const int*   ei  = (const int*)d_in[1];
    const int*   bat = (const int*)d_in[2];
    const float* W1  = (const float*)d_in[3];
    const float* b1  = (const float*)d_in[4];
    const float* W2  = (const float*)d_in[5];
    const float* b2  = (const float*)d_in[6];
    const float* W3  = (const float*)d_in[7];
    const float* b3  = (const float*)d_in[8];
    const float* lw1 = (const float*)d_in[9];
    const float* lb1 = (const float*)d_in[10];
    const float* lw2 = (const float*)d_in[11];
    const float* lb2 = (const float*)d_in[12];
    float* out = (float*)d_out;

    const int nN = in_sizes[2];       // 100000
    const int nE = in_sizes[1] / 2;   // 3200000
    const int G  = out_size;          // 4096
    const int* src = ei;
    const int* dst = ei + nE;

    const int nP = (nN + 1023) / 1024;

    // workspace layout
    char* p = (char*)d_ws;
    auto alloc = [&](size_t bytes) { char* r = p; p += (bytes + 255) & ~(size_t)255; return r; };
    float* buf0      = (float*)alloc(sizeof(float) * (size_t)nN * HID);
    float* buf1      = (float*)alloc(sizeof(float) * (size_t)nN * HID);
    float* dinv      = (float*)alloc(sizeof(float) * nN);
    float* sums      = (float*)alloc(sizeof(float) * (size_t)G * HID);
    float* cnt       = (float*)alloc(sizeof(float) * G);
    int*   cnt_int   = (int*)alloc(sizeof(int) * nN);
    size_t base_need = (size_t)(p - (char*)d_ws);
    int*   row_start = (int*)alloc(sizeof(int) * (nN + 1));
    int*   cursor    = (int*)alloc(sizeof(int) * nN);
    int*   partials  = (int*)alloc(sizeof(int) * (nP + 1));
    int*   esrc      = (int*)alloc(sizeof(int) * (size_t)nE);
    size_t full_need = (size_t)(p - (char*)d_ws);

    const int gemmGrid = (nN + 7) / 8;
    const int aggGrid  = (int)(((long long)nN * 64 + 255) / 256);

    // degree histogram (shared by both paths)
    hipMemsetAsync(cnt_int, 0, sizeof(int) * nN, stream);
    k_hist<<<(nE + 255) / 256, 256, 0, stream>>>(dst, cnt_int, nE);
    k_dinv<<<(nN + 255) / 256, 256, 0, stream>>>(cnt_int, dinv, nN);

    if (ws_size >= full_need) {
        // ---- CSR gather path ----
        k_scan1<<<nP, 256, 0, stream>>>(cnt_int, row_start, partials, nN);
        k_scan2<<<1, 1, 0, stream>>>(partials, nP);
        k_scan3<<<(nN + 255) / 256, 256, 0, stream>>>(row_start, partials, cursor, nN, nE);
        k_bucket<<<(nE + 255) / 256, 256, 0, stream>>>(src, dst, cursor, esrc, nE);

        hipMemsetAsync(sums, 0, sizeof(float) * ((size_t)G * HID + G), stream);
        k_count<<<(nN + 255) / 256, 256, 0, stream>>>(bat, cnt, nN);

        k_gemm<<<gemmGrid, 256, 0, stream>>>(x, W1, buf0, nN);
        k_agg<<<aggGrid, 256, 0, stream>>>(row_start, esrc, dinv, buf0, b1, buf1, nN, nullptr, nullptr);
        k_gemm<<<gemmGrid, 256, 0, stream>>>(buf1, W2, buf0, nN);
        k_agg<<<aggGrid, 256, 0, stream>>>(row_start, esrc, dinv, buf0, b2, buf1, nN, nullptr, nullptr);
        k_gemm<<<gemmGrid, 256, 0, stream>>>(buf1, W3, buf0, nN);
        k_agg<<<aggGrid, 256, 0, stream>>>(row_start, esrc, dinv, buf0, b3, nullptr, nN, sums, bat);
    } else {
        // ---- legacy atomic path (fits in base_need) ----
        (void)base_need;
        const int elemGrid = (nN * HID + 255) / 256;
        const int scatGrid = (int)(((long long)nE * 64 + 255) / 256);
        const size_t hbytes = sizeof(float) * (size_t)nN * HID;

        k_gemm<<<gemmGrid, 256, 0, stream>>>(x, W1, buf0, nN);
        hipMemsetAsync(buf1, 0, hbytes, stream);
        k_scatter<<<scatGrid, 256, 0, stream>>>(src, dst, dinv, buf0, buf1, nE);
        k_fuse<<<elemGrid, 256, 0, stream>>>(buf1, buf0, dinv, b1, buf0, nN);

        k_gemm<<<gemmGrid, 256, 0, stream>>>(buf0, W2, buf1, nN);
        hipMemsetAsync(buf0, 0, hbytes, stream);
        k_scatter<<<scatGrid, 256, 0, stream>>>(src, dst, dinv, buf1, buf0, nE);
        k_fuse<<<elemGrid, 256, 0, stream>>>(buf0, buf1, dinv, b2, buf1, nN);

        k_gemm<<<gemmGrid, 256, 0, stream>>>(buf1, W3, buf0, nN);
        hipMemsetAsync(buf1, 0, hbytes, stream);
        k_scatter<<<scatGrid, 256, 0, stream>>>(src, dst, dinv, buf0, buf1, nE);
        k_fuse<<<elemGrid, 256, 0, stream>>>(buf1, buf0, dinv, b3, buf0, nN);

        hipMemsetAsync(sums, 0, sizeof(float) * ((size_t)G * HID + G), stream);
        k_count<<<(nN + 255) / 256, 256, 0, stream>>>(bat, cnt, nN);
        k_poolsum<<<elemGrid, 256, 0, stream>>>(bat, buf0, sums, nN);
    }

    k_mlp<<<G, 64, 0, stream>>>(sums, cnt, lw1, lb1, lw2, lb2, out);
}

// Round 3
// 1289.442 us; speedup vs baseline: 6.9294x; 1.5464x over previous
//
#include <hip/hip_runtime.h>

// GCN regressor: CSR-by-dst gather-reduce + LDS-tiled f32 GEMM.
// Per call: build dst-CSR (hist -> scan -> bucket), then 3x (GEMM -> fused
// gather/agg+bias+ReLU), pool fused into layer-3 agg, MLP head.

constexpr int HID = 128;

static __device__ __forceinline__ void fma4(float4& a, float s, const float4& b) {
    a.x += s * b.x; a.y += s * b.y; a.z += s * b.z; a.w += s * b.w;
}

// ---------------- CSR build ----------------
__global__ __launch_bounds__(256) void k_hist(const int* __restrict__ dst,
                                              int* __restrict__ cnt, int nE) {
    int i = blockIdx.x * 256 + threadIdx.x;
    if (i < nE) atomicAdd(&cnt[dst[i]], 1);
}

__global__ __launch_bounds__(256) void k_dinv(const int* __restrict__ cnt,
                                              float* __restrict__ dinv, int n) {
    int i = blockIdx.x * 256 + threadIdx.x;
    if (i < n) dinv[i] = rsqrtf((float)cnt[i] + 1.0f);  // +1 self-loop
}

// chunked exclusive scan: 1024 elems/block (256 thr x 4)
__global__ __launch_bounds__(256) void k_scan1(const int* __restrict__ cnt,
                                               int* __restrict__ offs,
                                               int* __restrict__ partials, int n) {
    __shared__ int lds[256];
    int tid = threadIdx.x;
    int base = blockIdx.x * 1024 + tid * 4;
    int a0 = (base + 0 < n) ? cnt[base + 0] : 0;
    int a1 = (base + 1 < n) ? cnt[base + 1] : 0;
    int a2 = (base + 2 < n) ? cnt[base + 2] : 0;
    int a3 = (base + 3 < n) ? cnt[base + 3] : 0;
    int s = a0 + a1 + a2 + a3;
    lds[tid] = s;
    __syncthreads();
    for (int off = 1; off < 256; off <<= 1) {
        int v = (tid >= off) ? lds[tid - off] : 0;
        __syncthreads();
        lds[tid] += v;
        __syncthreads();
    }
    int excl = lds[tid] - s;
    if (tid == 255) partials[blockIdx.x] = lds[255];
    if (base + 0 < n) offs[base + 0] = excl;
    if (base + 1 < n) offs[base + 1] = excl + a0;
    if (base + 2 < n) offs[base + 2] = excl + a0 + a1;
    if (base + 3 < n) offs[base + 3] = excl + a0 + a1 + a2;
}

__global__ void k_scan2(int* partials, int nP) {
    int run = 0;
    for (int i = 0; i < nP; ++i) { int t = partials[i]; partials[i] = run; run += t; }
}

__global__ __launch_bounds__(256) void k_scan3(int* __restrict__ offs,
                                               const int* __restrict__ partials,
                                               int* __restrict__ cursor, int n, int nE) {
    int i = blockIdx.x * 256 + threadIdx.x;
    if (i < n) {
        int v = offs[i] + partials[i >> 10];
        offs[i] = v;
        cursor[i] = v;
    }
    if (i == 0) offs[n] = nE;
}

__global__ __launch_bounds__(256) void k_bucket(const int* __restrict__ src,
                                                const int* __restrict__ dst,
                                                int* __restrict__ cursor,
                                                int* __restrict__ esrc, int nE) {
    int e = blockIdx.x * 256 + threadIdx.x;
    if (e >= nE) return;
    int pos = atomicAdd(&cursor[dst[e]], 1);
    esrc[pos] = src[e];
}

// ---------------- GEMM: C[n,128] = A[n,128] @ W[128,128] ----------------
// 64-row x 128-col block tile, K in 2 passes of 64. 256 threads, 4x8 micro-tile.
__global__ __launch_bounds__(256) void k_gemm2(const float* __restrict__ A,
                                               const float* __restrict__ W,
                                               float* __restrict__ C, int n) {
    __shared__ float As[64][68];    // [row][k], padded to 68 (f4-aligned, bank-spread)
    __shared__ float Ws[64][128];   // [k][col]
    const int tid = threadIdx.x;
    const int tc = tid & 15;        // 16 col groups of 4 (+64 for second half)
    const int tr = tid >> 4;        // 16 row groups of 4
    const int row0 = blockIdx.x * 64;

    float4 acc0[4] = {}, acc1[4] = {};

    for (int pass = 0; pass < 2; ++pass) {
        const int kb = pass * 64;
        // stage A tile (64 rows x 64 k): 1024 f4, 4 iters, coalesced
        for (int it = 0; it < 4; ++it) {
            int flat = it * 256 + tid;
            int r = flat >> 4, k4 = flat & 15;
            int gr = row0 + r;
            float4 v = make_float4(0.f, 0.f, 0.f, 0.f);
            if (gr < n) v = *(const float4*)(A + (size_t)gr * HID + kb + k4 * 4);
            *(float4*)(&As[r][k4 * 4]) = v;
        }
        // stage W tile (64 k x 128 c): 2048 f4, 8 iters, coalesced
        for (int it = 0; it < 8; ++it) {
            int flat = it * 256 + tid;
            int k = flat >> 5, c4 = flat & 31;
            *(float4*)(&Ws[k][c4 * 4]) = *(const float4*)(W + (size_t)(kb + k) * HID + c4 * 4);
        }
        __syncthreads();

#pragma unroll 2
        for (int k4 = 0; k4 < 16; ++k4) {
            float ar[4][4];
            *(float4*)&ar[0][0] = *(const float4*)(&As[tr * 4 + 0][k4 * 4]);
            *(float4*)&ar[1][0] = *(const float4*)(&As[tr * 4 + 1][k4 * 4]);
            *(float4*)&ar[2][0] = *(const float4*)(&As[tr * 4 + 2][k4 * 4]);
            *(float4*)&ar[3][0] = *(const float4*)(&As[tr * 4 + 3][k4 * 4]);
#pragma unroll
            for (int j = 0; j < 4; ++j) {
                float4 b0 = *(const float4*)(&Ws[k4 * 4 + j][tc * 4]);
                float4 b1 = *(const float4*)(&Ws[k4 * 4 + j][64 + tc * 4]);
#pragma unroll
                for (int i = 0; i < 4; ++i) {
                    fma4(acc0[i], ar[i][j], b0);
                    fma4(acc1[i], ar[i][j], b1);
                }
            }
        }
        __syncthreads();
    }

#pragma unroll
    for (int i = 0; i < 4; ++i) {
        int r = row0 + tr * 4 + i;
        if (r < n) {
            *(float4*)(C + (size_t)r * HID + tc * 4) = acc0[i];
            *(float4*)(C + (size_t)r * HID + 64 + tc * 4) = acc1[i];
        }
    }
}

// ---------------- fused gather-aggregate + bias + ReLU (+ optional pool) ---
// one wave per dst node; lane owns 2 channels.
__global__ __launch_bounds__(256) void k_agg(const int* __restrict__ row_start,
                                             const int* __restrict__ esrc,
                                             const float* __restrict__ dinv,
                                             const float* __restrict__ hw,
                                             const float* __restrict__ bias,
                                             float* __restrict__ out, int n,
                                             float* __restrict__ pool_sums,
                                             const int* __restrict__ batch) {
    int t = blockIdx.x * 256 + threadIdx.x;
    int node = t >> 6;
    if (node >= n) return;
    int c = (t & 63) * 2;
    int e0 = row_start[node], e1 = row_start[node + 1];
    float dd = dinv[node];
    float ax = 0.f, ay = 0.f;
    int e = e0;
    for (; e + 4 <= e1; e += 4) {
        int sa = esrc[e], sb = esrc[e + 1], sc = esrc[e + 2], sd = esrc[e + 3];
        float wa = dinv[sa], wb = dinv[sb], wc = dinv[sc], wd = dinv[sd];
        float2 va = *(const float2*)(hw + (size_t)sa * HID + c);
        float2 vb = *(const float2*)(hw + (size_t)sb * HID + c);
        float2 vc = *(const float2*)(hw + (size_t)sc * HID + c);
        float2 vd = *(const float2*)(hw + (size_t)sd * HID + c);
        ax += va.x * wa + vb.x * wb + vc.x * wc + vd.x * wd;
        ay += va.y * wa + vb.y * wb + vc.y * wc + vd.y * wd;
    }
    for (; e < e1; ++e) {
        int sa = esrc[e];
        float wa = dinv[sa];
        float2 va = *(const float2*)(hw + (size_t)sa * HID + c);
        ax += va.x * wa;
        ay += va.y * wa;
    }
    ax *= dd; ay *= dd;   // factor dst-side norm out of the loop
    float2 hv = *(const float2*)(hw + (size_t)node * HID + c);
    ax += hv.x * dd * dd + bias[c];
    ay += hv.y * dd * dd + bias[c + 1];
    ax = fmaxf(ax, 0.f);
    ay = fmaxf(ay, 0.f);
    if (pool_sums) {
        float* p = &pool_sums[(size_t)batch[node] * HID + c];
        atomicAdd(p, ax);
        atomicAdd(p + 1, ay);
    } else {
        *(float2*)(out + (size_t)node * HID + c) = make_float2(ax, ay);
    }
}

// ---------------- pooling / head ----------------
__global__ __launch_bounds__(256) void k_count(const int* __restrict__ batch,
                                               float* __restrict__ cnt, int n) {
    int i = blockIdx.x * 256 + threadIdx.x;
    if (i < n) atomicAdd(&cnt[batch[i]], 1.0f);
}

__global__ __launch_bounds__(64) void k_mlp(const float* __restrict__ sums,
                                            const float* __restrict__ cnt,
                                            const float* __restrict__ lw1,
                                            const float* __restrict__ lb1,
                                            const float* __restrict__ lw2,
                                            const float* __restrict__ lb2,
                                            float* __restrict__ out) {
    int g = blockIdx.x;
    int j = threadIdx.x;
    float inv = 1.0f / fmaxf(cnt[g], 1.0f);
    const float* srow = sums + (size_t)g * HID;
    float acc = lb1[j];
#pragma unroll 8
    for (int k = 0; k < HID; ++k) acc += srow[k] * inv * lw1[k * 64 + j];
    acc = fmaxf(acc, 0.0f);
    float prod = acc * lw2[j];
#pragma unroll
    for (int off = 32; off > 0; off >>= 1) prod += __shfl_down(prod, off);
    if (j == 0) out[g] = prod + lb2[0];
}

// ---------------- legacy fallback (atomic scatter) ----------------
__global__ __launch_bounds__(256) void k_scatter(const int* __restrict__ src,
                                                 const int* __restrict__ dst,
                                                 const float* __restrict__ dinv,
                                                 const float* __restrict__ hw,
                                                 float* __restrict__ agg, int nE) {
    long long t = (long long)blockIdx.x * 256 + threadIdx.x;
    int e = (int)(t >> 6);
    if (e >= nE) return;
    int c = ((int)t & 63) * 2;
    int s = src[e], d = dst[e];
    float w = dinv[s] * dinv[d];
    const float2 v = *(const float2*)(hw + (size_t)s * HID + c);
    float* p = agg + (size_t)d * HID + c;
    atomicAdd(p, v.x * w);
    atomicAdd(p + 1, v.y * w);
}

__global__ __launch_bounds__(256) void k_fuse(const float* __restrict__ agg,
                                              const float* hw,
                                              const float* __restrict__ dinv,
                                              const float* __restrict__ b,
                                              float* out, int n) {
    int t = blockIdx.x * 256 + threadIdx.x;
    if (t >= n * HID) return;
    int node = t >> 7, c = t & (HID - 1);
    float di = dinv[node];
    float v = agg[t] + hw[t] * di * di + b[c];
    out[t] = fmaxf(v, 0.0f);
}

__global__ __launch_bounds__(256) void k_poolsum(const int* __restrict__ batch,
                                                 const float* __restrict__ h,
                                                 float* __restrict__ sums, int n) {
    int t = blockIdx.x * 256 + threadIdx.x;
    if (t >= n * HID) return;
    int node = t >> 7, c = t & (HID - 1);
    atomicAdd(&sums[(size_t)batch[node] * HID + c], h[t]);
}

extern "C" void kernel_launch(void* const* d_in, const int* in_sizes, int n_in,
                              void* d_out, int out_size, void* d_ws, size_t ws_size,
                              hipStream_t stream) {
    const float* x   = (const float*)d_in[0];
    const int*   ei  = (const int*)d_in[1];
    const int*   bat = (const int*)d_in[2];
    const float* W1  = (const float*)d_in[3];
    const float* b1  = (const float*)d_in[4];
    const float* W2  = (const float*)d_in[5];
    const float* b2  = (const float*)d_in[6];
    const float* W3  = (const float*)d_in[7];
    const float* b3  = (const float*)d_in[8];
    const float* lw1 = (const float*)d_in[9];
    const float* lb1 = (const float*)d_in[10];
    const float* lw2 = (const float*)d_in[11];
    const float* lb2 = (const float*)d_in[12];
    float* out = (float*)d_out;

    const int nN = in_sizes[2];       // 100000
    const int nE = in_sizes[1] / 2;   // 3200000
    const int G  = out_size;          // 4096
    const int* src = ei;
    const int* dst = ei + nE;

    const int nP = (nN + 1023) / 1024;

    // workspace layout
    char* p = (char*)d_ws;
    auto alloc = [&](size_t bytes) { char* r = p; p += (bytes + 255) & ~(size_t)255; return r; };
    float* buf0      = (float*)alloc(sizeof(float) * (size_t)nN * HID);
    float* buf1      = (float*)alloc(sizeof(float) * (size_t)nN * HID);
    float* dinv      = (float*)alloc(sizeof(float) * nN);
    float* sums      = (float*)alloc(sizeof(float) * (size_t)G * HID);
    float* cnt       = (float*)alloc(sizeof(float) * G);
    int*   cnt_int   = (int*)alloc(sizeof(int) * nN);
    int*   row_start = (int*)alloc(sizeof(int) * (nN + 1));
    int*   cursor    = (int*)alloc(sizeof(int) * nN);
    int*   partials  = (int*)alloc(sizeof(int) * (nP + 1));
    int*   esrc      = (int*)alloc(sizeof(int) * (size_t)nE);
    size_t full_need = (size_t)(p - (char*)d_ws);

    const int gemmGrid = (nN + 63) / 64;
    const int aggGrid  = (int)(((long long)nN * 64 + 255) / 256);

    // degree histogram (shared by both paths)
    hipMemsetAsync(cnt_int, 0, sizeof(int) * nN, stream);
    k_hist<<<(nE + 255) / 256, 256, 0, stream>>>(dst, cnt_int, nE);
    k_dinv<<<(nN + 255) / 256, 256, 0, stream>>>(cnt_int, dinv, nN);

    if (ws_size >= full_need) {
        // ---- CSR gather path ----
        k_scan1<<<nP, 256, 0, stream>>>(cnt_int, row_start, partials, nN);
        k_scan2<<<1, 1, 0, stream>>>(partials, nP);
        k_scan3<<<(nN + 255) / 256, 256, 0, stream>>>(row_start, partials, cursor, nN, nE);
        k_bucket<<<(nE + 255) / 256, 256, 0, stream>>>(src, dst, cursor, esrc, nE);

        hipMemsetAsync(sums, 0, sizeof(float) * ((size_t)G * HID + G), stream);
        k_count<<<(nN + 255) / 256, 256, 0, stream>>>(bat, cnt, nN);

        k_gemm2<<<gemmGrid, 256, 0, stream>>>(x, W1, buf0, nN);
        k_agg<<<aggGrid, 256, 0, stream>>>(row_start, esrc, dinv, buf0, b1, buf1, nN, nullptr, nullptr);
        k_gemm2<<<gemmGrid, 256, 0, stream>>>(buf1, W2, buf0, nN);
        k_agg<<<aggGrid, 256, 0, stream>>>(row_start, esrc, dinv, buf0, b2, buf1, nN, nullptr, nullptr);
        k_gemm2<<<gemmGrid, 256, 0, stream>>>(buf1, W3, buf0, nN);
        k_agg<<<aggGrid, 256, 0, stream>>>(row_start, esrc, dinv, buf0, b3, nullptr, nN, sums, bat);
    } else {
        // ---- legacy atomic path ----
        const int elemGrid = (nN * HID + 255) / 256;
        const int scatGrid = (int)(((long long)nE * 64 + 255) / 256);
        const size_t hbytes = sizeof(float) * (size_t)nN * HID;

        k_gemm2<<<gemmGrid, 256, 0, stream>>>(x, W1, buf0, nN);
        hipMemsetAsync(buf1, 0, hbytes, stream);
        k_scatter<<<scatGrid, 256, 0, stream>>>(src, dst, dinv, buf0, buf1, nE);
        k_fuse<<<elemGrid, 256, 0, stream>>>(buf1, buf0, dinv, b1, buf0, nN);

        k_gemm2<<<gemmGrid, 256, 0, stream>>>(buf0, W2, buf1, nN);
        hipMemsetAsync(buf0, 0, hbytes, stream);
        k_scatter<<<scatGrid, 256, 0, stream>>>(src, dst, dinv, buf1, buf0, nE);
        k_fuse<<<elemGrid, 256, 0, stream>>>(buf0, buf1, dinv, b2, buf1, nN);

        k_gemm2<<<gemmGrid, 256, 0, stream>>>(buf1, W3, buf0, nN);
        hipMemsetAsync(buf1, 0, hbytes, stream);
        k_scatter<<<scatGrid, 256, 0, stream>>>(src, dst, dinv, buf0, buf1, nE);
        k_fuse<<<elemGrid, 256, 0, stream>>>(buf1, buf0, dinv, b3, buf0, nN);

        hipMemsetAsync(sums, 0, sizeof(float) * ((size_t)G * HID + G), stream);
        k_count<<<(nN + 255) / 256, 256, 0, stream>>>(bat, cnt, nN);
        k_poolsum<<<elemGrid, 256, 0, stream>>>(bat, buf0, sums, nN);
    }

    k_mlp<<<G, 64, 0, stream>>>(sums, cnt, lw1, lb1, lw2, lb2, out);
}

// Round 6
// 1074.934 us; speedup vs baseline: 8.3122x; 1.1996x over previous
//
#include <hip/hip_runtime.h>

// GCN regressor: CSR-by-dst gather-reduce + LDS-tiled f32 GEMM.
// CSR build = hist -> scan -> binned 2-phase placement (stage + place),
// then 3x (GEMM -> fused gather/agg+bias+ReLU), pool fused into layer-3 agg,
// MLP head.

constexpr int HID = 128;
constexpr int BIN_SHIFT = 8;          // 256 dst nodes per bin
constexpr int MAXBINS = 512;

static __device__ __forceinline__ void fma4(float4& a, float s, const float4& b) {
    a.x += s * b.x; a.y += s * b.y; a.z += s * b.z; a.w += s * b.w;
}

// ---------------- CSR build ----------------
__global__ __launch_bounds__(256) void k_hist(const int* __restrict__ dst,
                                              int* __restrict__ cnt, int nE) {
    int i = blockIdx.x * 256 + threadIdx.x;
    if (i < nE) atomicAdd(&cnt[dst[i]], 1);
}

__global__ __launch_bounds__(256) void k_dinv(const int* __restrict__ cnt,
                                              float* __restrict__ dinv, int n) {
    int i = blockIdx.x * 256 + threadIdx.x;
    if (i < n) dinv[i] = rsqrtf((float)cnt[i] + 1.0f);  // +1 self-loop
}

// chunked exclusive scan: 1024 elems/block (256 thr x 4)
__global__ __launch_bounds__(256) void k_scan1(const int* __restrict__ cnt,
                                               int* __restrict__ offs,
                                               int* __restrict__ partials, int n) {
    __shared__ int lds[256];
    int tid = threadIdx.x;
    int base = blockIdx.x * 1024 + tid * 4;
    int a0 = (base + 0 < n) ? cnt[base + 0] : 0;
    int a1 = (base + 1 < n) ? cnt[base + 1] : 0;
    int a2 = (base + 2 < n) ? cnt[base + 2] : 0;
    int a3 = (base + 3 < n) ? cnt[base + 3] : 0;
    int s = a0 + a1 + a2 + a3;
    lds[tid] = s;
    __syncthreads();
    for (int off = 1; off < 256; off <<= 1) {
        int v = (tid >= off) ? lds[tid - off] : 0;
        __syncthreads();
        lds[tid] += v;
        __syncthreads();
    }
    int excl = lds[tid] - s;
    if (tid == 255) partials[blockIdx.x] = lds[255];
    if (base + 0 < n) offs[base + 0] = excl;
    if (base + 1 < n) offs[base + 1] = excl + a0;
    if (base + 2 < n) offs[base + 2] = excl + a0 + a1;
    if (base + 3 < n) offs[base + 3] = excl + a0 + a1 + a2;
}

__global__ void k_scan2(int* partials, int nP) {
    int run = 0;
    for (int i = 0; i < nP; ++i) { int t = partials[i]; partials[i] = run; run += t; }
}

__global__ __launch_bounds__(256) void k_scan3(int* __restrict__ offs,
                                               const int* __restrict__ partials,
                                               int n, int nE) {
    int i = blockIdx.x * 256 + threadIdx.x;
    if (i < n) offs[i] += partials[i >> 10];
    if (i == 0) offs[n] = nE;
}

__global__ __launch_bounds__(256) void k_bininit(const int* __restrict__ row_start,
                                                 int* __restrict__ bin_cursor,
                                                 int nbins, int nN) {
    int b = blockIdx.x * 256 + threadIdx.x;
    if (b < nbins) bin_cursor[b] = row_start[min(b << BIN_SHIFT, nN)];
}

// Phase 1: bin (src,dst) pairs into dst-range bins; per-WG span reservation
// keeps staged writes XCD-local and line-dense.
__global__ __launch_bounds__(256) void k_stage(const int* __restrict__ src,
                                               const int* __restrict__ dst,
                                               int* __restrict__ bin_cursor,
                                               int2* __restrict__ staged,
                                               int nE, int nbins) {
    __shared__ int hist[MAXBINS];
    __shared__ int wbase[MAXBINS];
    __shared__ int rank[MAXBINS];
    const int tid = threadIdx.x;
    const long long e0 = (long long)blockIdx.x * 4096;
    int es[16], ed[16];
#pragma unroll
    for (int k = 0; k < 16; ++k) {
        long long e = e0 + k * 256 + tid;
        if (e < nE) { es[k] = src[e]; ed[k] = dst[e]; }
        else        { es[k] = 0; ed[k] = -1; }
    }
    for (int t = tid; t < nbins; t += 256) { hist[t] = 0; rank[t] = 0; }
    __syncthreads();
#pragma unroll
    for (int k = 0; k < 16; ++k)
        if (ed[k] >= 0) atomicAdd(&hist[ed[k] >> BIN_SHIFT], 1);
    __syncthreads();
    for (int t = tid; t < nbins; t += 256)
        wbase[t] = hist[t] ? atomicAdd(&bin_cursor[t], hist[t]) : 0;
    __syncthreads();
#pragma unroll
    for (int k = 0; k < 16; ++k)
        if (ed[k] >= 0) {
            int b = ed[k] >> BIN_SHIFT;
            int r = atomicAdd(&rank[b], 1);
            staged[wbase[b] + r] = make_int2(es[k], ed[k]);
        }
}

// Phase 2: one WG per bin; LDS cursors hand out final CSR slots; all esrc
// writes fall in this WG's private region (no cross-XCD sharing).
__global__ __launch_bounds__(256) void k_place(const int* __restrict__ row_start,
                                               const int2* __restrict__ staged,
                                               int* __restrict__ esrc, int nN) {
    __shared__ int cur[1 << BIN_SHIFT];
    const int d0 = blockIdx.x << BIN_SHIFT;
    const int dend = min(d0 + (1 << BIN_SHIFT), nN);
    const int tid = threadIdx.x;
    int d = d0 + tid;
    cur[tid] = (d < dend) ? row_start[d] : 0;
    __syncthreads();
    const int p0 = row_start[d0];
    const int p1 = row_start[dend];
    for (int i = p0 + tid; i < p1; i += 256) {
        int2 pr = staged[i];
        int pos = atomicAdd(&cur[pr.y - d0], 1);
        esrc[pos] = pr.x;
    }
}

// ---------------- GEMM: C[n,128] = A[n,128] @ W[128,128] ----------------
// 64-row x 128-col block tile, K in 2 passes of 64. 256 threads, 4x8 micro-tile.
__global__ __launch_bounds__(256) void k_gemm2(const float* __restrict__ A,
                                               const float* __restrict__ W,
                                               float* __restrict__ C, int n) {
    __shared__ float As[64][68];
    __shared__ float Ws[64][128];
    const int tid = threadIdx.x;
    const int tc = tid & 15;
    const int tr = tid >> 4;
    const int row0 = blockIdx.x * 64;

    float4 acc0[4] = {}, acc1[4] = {};

    for (int pass = 0; pass < 2; ++pass) {
        const int kb = pass * 64;
        for (int it = 0; it < 4; ++it) {
            int flat = it * 256 + tid;
            int r = flat >> 4, k4 = flat & 15;
            int gr = row0 + r;
            float4 v = make_float4(0.f, 0.f, 0.f, 0.f);
            if (gr < n) v = *(const float4*)(A + (size_t)gr * HID + kb + k4 * 4);
            *(float4*)(&As[r][k4 * 4]) = v;
        }
        for (int it = 0; it < 8; ++it) {
            int flat = it * 256 + tid;
            int k = flat >> 5, c4 = flat & 31;
            *(float4*)(&Ws[k][c4 * 4]) = *(const float4*)(W + (size_t)(kb + k) * HID + c4 * 4);
        }
        __syncthreads();

#pragma unroll 2
        for (int k4 = 0; k4 < 16; ++k4) {
            float ar[4][4];
            *(float4*)&ar[0][0] = *(const float4*)(&As[tr * 4 + 0][k4 * 4]);
            *(float4*)&ar[1][0] = *(const float4*)(&As[tr * 4 + 1][k4 * 4]);
            *(float4*)&ar[2][0] = *(const float4*)(&As[tr * 4 + 2][k4 * 4]);
            *(float4*)&ar[3][0] = *(const float4*)(&As[tr * 4 + 3][k4 * 4]);
#pragma unroll
            for (int j = 0; j < 4; ++j) {
                float4 b0 = *(const float4*)(&Ws[k4 * 4 + j][tc * 4]);
                float4 b1 = *(const float4*)(&Ws[k4 * 4 + j][64 + tc * 4]);
#pragma unroll
                for (int i = 0; i < 4; ++i) {
                    fma4(acc0[i], ar[i][j], b0);
                    fma4(acc1[i], ar[i][j], b1);
                }
            }
        }
        __syncthreads();
    }

#pragma unroll
    for (int i = 0; i < 4; ++i) {
        int r = row0 + tr * 4 + i;
        if (r < n) {
            *(float4*)(C + (size_t)r * HID + tc * 4) = acc0[i];
            *(float4*)(C + (size_t)r * HID + 64 + tc * 4) = acc1[i];
        }
    }
}

// ---------------- fused gather-aggregate + bias + ReLU (+ optional pool) ---
__global__ __launch_bounds__(256) void k_agg(const int* __restrict__ row_start,
                                             const int* __restrict__ esrc,
                                             const float* __restrict__ dinv,
                                             const float* __restrict__ hw,
                                             const float* __restrict__ bias,
                                             float* __restrict__ out, int n,
                                             float* __restrict__ pool_sums,
                                             const int* __restrict__ batch) {
    int t = blockIdx.x * 256 + threadIdx.x;
    int node = t >> 6;
    if (node >= n) return;
    int c = (t & 63) * 2;
    int e0 = row_start[node], e1 = row_start[node + 1];
    float dd = dinv[node];
    float ax = 0.f, ay = 0.f;
    int e = e0;
    for (; e + 4 <= e1; e += 4) {
        int sa = esrc[e], sb = esrc[e + 1], sc = esrc[e + 2], sd = esrc[e + 3];
        float wa = dinv[sa], wb = dinv[sb], wc = dinv[sc], wd = dinv[sd];
        float2 va = *(const float2*)(hw + (size_t)sa * HID + c);
        float2 vb = *(const float2*)(hw + (size_t)sb * HID + c);
        float2 vc = *(const float2*)(hw + (size_t)sc * HID + c);
        float2 vd = *(const float2*)(hw + (size_t)sd * HID + c);
        ax += va.x * wa + vb.x * wb + vc.x * wc + vd.x * wd;
        ay += va.y * wa + vb.y * wb + vc.y * wc + vd.y * wd;
    }
    for (; e < e1; ++e) {
        int sa = esrc[e];
        float wa = dinv[sa];
        float2 va = *(const float2*)(hw + (size_t)sa * HID + c);
        ax += va.x * wa;
        ay += va.y * wa;
    }
    ax *= dd; ay *= dd;
    float2 hv = *(const float2*)(hw + (size_t)node * HID + c);
    ax += hv.x * dd * dd + bias[c];
    ay += hv.y * dd * dd + bias[c + 1];
    ax = fmaxf(ax, 0.f);
    ay = fmaxf(ay, 0.f);
    if (pool_sums) {
        float* p = &pool_sums[(size_t)batch[node] * HID + c];
        atomicAdd(p, ax);
        atomicAdd(p + 1, ay);
    } else {
        *(float2*)(out + (size_t)node * HID + c) = make_float2(ax, ay);
    }
}

// ---------------- pooling / head ----------------
__global__ __launch_bounds__(256) void k_count(const int* __restrict__ batch,
                                               float* __restrict__ cnt, int n) {
    int i = blockIdx.x * 256 + threadIdx.x;
    if (i < n) atomicAdd(&cnt[batch[i]], 1.0f);
}

__global__ __launch_bounds__(64) void k_mlp(const float* __restrict__ sums,
                                            const float* __restrict__ cnt,
                                            const float* __restrict__ lw1,
                                            const float* __restrict__ lb1,
                                            const float* __restrict__ lw2,
                                            const float* __restrict__ lb2,
                                            float* __restrict__ out) {
    int g = blockIdx.x;
    int j = threadIdx.x;
    float inv = 1.0f / fmaxf(cnt[g], 1.0f);
    const float* srow = sums + (size_t)g * HID;
    float acc = lb1[j];
#pragma unroll 8
    for (int k = 0; k < HID; ++k) acc += srow[k] * inv * lw1[k * 64 + j];
    acc = fmaxf(acc, 0.0f);
    float prod = acc * lw2[j];
#pragma unroll
    for (int off = 32; off > 0; off >>= 1) prod += __shfl_down(prod, off);
    if (j == 0) out[g] = prod + lb2[0];
}

// ---------------- legacy fallbacks ----------------
__global__ __launch_bounds__(256) void k_bucket(const int* __restrict__ src,
                                                const int* __restrict__ dst,
                                                int* __restrict__ cursor,
                                                int* __restrict__ esrc, int nE) {
    int e = blockIdx.x * 256 + threadIdx.x;
    if (e >= nE) return;
    int pos = atomicAdd(&cursor[dst[e]], 1);
    esrc[pos] = src[e];
}

__global__ __launch_bounds__(256) void k_scatter(const int* __restrict__ src,
                                                 const int* __restrict__ dst,
                                                 const float* __restrict__ dinv,
                                                 const float* __restrict__ hw,
                                                 float* __restrict__ agg, int nE) {
    long long t = (long long)blockIdx.x * 256 + threadIdx.x;
    int e = (int)(t >> 6);
    if (e >= nE) return;
    int c = ((int)t & 63) * 2;
    int s = src[e], d = dst[e];
    float w = dinv[s] * dinv[d];
    const float2 v = *(const float2*)(hw + (size_t)s * HID + c);
    float* p = agg + (size_t)d * HID + c;
    atomicAdd(p, v.x * w);
    atomicAdd(p + 1, v.y * w);
}

__global__ __launch_bounds__(256) void k_fuse(const float* __restrict__ agg,
                                              const float* hw,
                                              const float* __restrict__ dinv,
                                              const float* __restrict__ b,
                                              float* out, int n) {
    int t = blockIdx.x * 256 + threadIdx.x;
    if (t >= n * HID) return;
    int node = t >> 7, c = t & (HID - 1);
    float di = dinv[node];
    float v = agg[t] + hw[t] * di * di + b[c];
    out[t] = fmaxf(v, 0.0f);
}

__global__ __launch_bounds__(256) void k_poolsum(const int* __restrict__ batch,
                                                 const float* __restrict__ h,
                                                 float* __restrict__ sums, int n) {
    int t = blockIdx.x * 256 + threadIdx.x;
    if (t >= n * HID) return;
    int node = t >> 7, c = t & (HID - 1);
    atomicAdd(&sums[(size_t)batch[node] * HID + c], h[t]);
}

extern "C" void kernel_launch(void* const* d_in, const int* in_sizes, int n_in,
                              void* d_out, int out_size, void* d_ws, size_t ws_size,
                              hipStream_t stream) {
    const float* x   = (const float*)d_in[0];
    const int*   ei  = (const int*)d_in[1];
    const int*   bat = (const int*)d_in[2];
    const float* W1  = (const float*)d_in[3];
    const float* b1  = (const float*)d_in[4];
    const float* W2  = (const float*)d_in[5];
    const float* b2  = (const float*)d_in[6];
    const float* W3  = (const float*)d_in[7];
    const float* b3  = (const float*)d_in[8];
    const float* lw1 = (const float*)d_in[9];
    const float* lb1 = (const float*)d_in[10];
    const float* lw2 = (const float*)d_in[11];
    const float* lb2 = (const float*)d_in[12];
    float* out = (float*)d_out;

    const int nN = in_sizes[2];       // 100000
    const int nE = in_sizes[1] / 2;   // 3200000
    const int G  = out_size;          // 4096
    const int* src = ei;
    const int* dst = ei + nE;

    const int nP = (nN + 1023) / 1024;
    const int nbins = (nN + (1 << BIN_SHIFT) - 1) >> BIN_SHIFT;

    // workspace layout
    char* p = (char*)d_ws;
    auto alloc = [&](size_t bytes) { char* r = p; p += (bytes + 255) & ~(size_t)255; return r; };
    float* buf0      = (float*)alloc(sizeof(float) * (size_t)nN * HID);
    float* buf1      = (float*)alloc(sizeof(float) * (size_t)nN * HID);
    float* dinv      = (float*)alloc(sizeof(float) * nN);
    float* sums      = (float*)alloc(sizeof(float) * (size_t)G * HID);
    float* cnt       = (float*)alloc(sizeof(float) * G);
    int*   cnt_int   = (int*)alloc(sizeof(int) * nN);
    int*   row_start = (int*)alloc(sizeof(int) * (nN + 1));
    int*   cursor    = (int*)alloc(sizeof(int) * nN);   // also bin_cursor (first nbins ints)
    int*   partials  = (int*)alloc(sizeof(int) * (nP + 1));
    int*   esrc      = (int*)alloc(sizeof(int) * (size_t)nE);
    size_t full_need = (size_t)(p - (char*)d_ws);
    int2*  staged    = (int2*)buf1;   // aliases buf1: consumed before agg writes buf1

    const int gemmGrid = (nN + 63) / 64;
    const int aggGrid  = (int)(((long long)nN * 64 + 255) / 256);

    hipMemsetAsync(cnt_int, 0, sizeof(int) * nN, stream);
    k_hist<<<(nE + 255) / 256, 256, 0, stream>>>(dst, cnt_int, nE);
    k_dinv<<<(nN + 255) / 256, 256, 0, stream>>>(cnt_int, dinv, nN);

    if (ws_size >= full_need) {
        // ---- CSR gather path ----
        k_scan1<<<nP, 256, 0, stream>>>(cnt_int, row_start, partials, nN);
        k_scan2<<<1, 1, 0, stream>>>(partials, nP);
        k_scan3<<<(nN + 255) / 256, 256, 0, stream>>>(row_start, partials, nN, nE);

        if (nbins <= MAXBINS) {
            k_bininit<<<(nbins + 255) / 256, 256, 0, stream>>>(row_start, cursor, nbins, nN);
            k_stage<<<(int)(((long long)nE + 4095) / 4096), 256, 0, stream>>>(src, dst, cursor, staged, nE, nbins);
            k_place<<<nbins, 256, 0, stream>>>(row_start, staged, esrc, nN);
        } else {
            // cursor must hold row_start values
            hipMemcpyAsync(cursor, row_start, sizeof(int) * nN, hipMemcpyDeviceToDevice, stream);
            k_bucket<<<(nE + 255) / 256, 256, 0, stream>>>(src, dst, cursor, esrc, nE);
        }

        hipMemsetAsync(sums, 0, sizeof(float) * ((size_t)G * HID + G), stream);
        k_count<<<(nN + 255) / 256, 256, 0, stream>>>(bat, cnt, nN);

        k_gemm2<<<gemmGrid, 256, 0, stream>>>(x, W1, buf0, nN);
        k_agg<<<aggGrid, 256, 0, stream>>>(row_start, esrc, dinv, buf0, b1, buf1, nN, nullptr, nullptr);
        k_gemm2<<<gemmGrid, 256, 0, stream>>>(buf1, W2, buf0, nN);
        k_agg<<<aggGrid, 256, 0, stream>>>(row_start, esrc, dinv, buf0, b2, buf1, nN, nullptr, nullptr);
        k_gemm2<<<gemmGrid, 256, 0, stream>>>(buf1, W3, buf0, nN);
        k_agg<<<aggGrid, 256, 0, stream>>>(row_start, esrc, dinv, buf0, b3, nullptr, nN, sums, bat);
    } else {
        // ---- legacy atomic path ----
        const int elemGrid = (nN * HID + 255) / 256;
        const int scatGrid = (int)(((long long)nE * 64 + 255) / 256);
        const size_t hbytes = sizeof(float) * (size_t)nN * HID;

        k_gemm2<<<gemmGrid, 256, 0, stream>>>(x, W1, buf0, nN);
        hipMemsetAsync(buf1, 0, hbytes, stream);
        k_scatter<<<scatGrid, 256, 0, stream>>>(src, dst, dinv, buf0, buf1, nE);
        k_fuse<<<elemGrid, 256, 0, stream>>>(buf1, buf0, dinv, b1, buf0, nN);

        k_gemm2<<<gemmGrid, 256, 0, stream>>>(buf0, W2, buf1, nN);
        hipMemsetAsync(buf0, 0, hbytes, stream);
        k_scatter<<<scatGrid, 256, 0, stream>>>(src, dst, dinv, buf1, buf0, nE);
        k_fuse<<<elemGrid, 256, 0, stream>>>(buf0, buf1, dinv, b2, buf1, nN);

        k_gemm2<<<gemmGrid, 256, 0, stream>>>(buf1, W3, buf0, nN);
        hipMemsetAsync(buf1, 0, hbytes, stream);
        k_scatter<<<scatGrid, 256, 0, stream>>>(src, dst, dinv, buf0, buf1, nE);
        k_fuse<<<elemGrid, 256, 0, stream>>>(buf1, buf0, dinv, b3, buf0, nN);

        hipMemsetAsync(sums, 0, sizeof(float) * ((size_t)G * HID + G), stream);
        k_count<<<(nN + 255) / 256, 256, 0, stream>>>(bat, cnt, nN);
        k_poolsum<<<elemGrid, 256, 0, stream>>>(bat, buf0, sums, nN);
    }

    k_mlp<<<G, 64, 0, stream>>>(sums, cnt, lw1, lb1, lw2, lb2, out);
}